// Round 2
// baseline (469.469 us; speedup 1.0000x reference)
//
#include <hip/hip_runtime.h>
#include <cstdint>

typedef _Float16 f16;
typedef _Float16 f16x8 __attribute__((ext_vector_type(8)));
typedef _Float16 f16x4 __attribute__((ext_vector_type(4)));
typedef float f32x4 __attribute__((ext_vector_type(4)));

#define NB   64      // batch
#define NT   512     // T
#define NH   512     // HID == OBS_DIM == MLP_HID
#define NE   8
#define NR   8
#define PADT 514     // T + 2 pad rows

__device__ __forceinline__ void load_lds16(const void* g, void* l) {
  __builtin_amdgcn_global_load_lds(
      (const __attribute__((address_space(1))) uint32_t*)g,
      (__attribute__((address_space(3))) uint32_t*)l, 16, 0, 0);
}

// ---------------- gating: relu(ue@gw1+gb1)@gw2+gb2 -> argmax -> eidx ----------
__global__ void gating_kernel(const float* __restrict__ ue, const float* __restrict__ gw1,
                              const float* __restrict__ gb1, const float* __restrict__ gw2,
                              const float* __restrict__ gb2, int* __restrict__ eidx) {
  const int b = blockIdx.x;
  __shared__ float ues[128];
  __shared__ float g1[128];
  __shared__ float zs[NE];
  const int j = threadIdx.x;  // 128
  ues[j] = ue[b * 128 + j];
  __syncthreads();
  float acc = gb1[j];
  for (int k = 0; k < 128; ++k) acc += ues[k] * gw1[k * 128 + j];
  g1[j] = fmaxf(acc, 0.f);
  __syncthreads();
  if (j < NE) {
    float z = gb2[j];
    for (int k = 0; k < 128; ++k) z += g1[k] * gw2[k * NE + j];
    zs[j] = z;
  }
  __syncthreads();
  if (j == 0) {
    int best = 0; float bz = zs[0];
    for (int e = 1; e < NE; ++e) if (zs[e] > bz) { bz = zs[e]; best = e; }
    eidx[b] = best;  // argmax(softmax(z/tau)) == argmax(z); rw is numerically one-hot
  }
}

// ---- fold MoLE weights: out[e][i][k] = w[k][i] + sum_r As[k][r]Bs[r][i] + Ae[e][k][r]Be[e][r][i]
template <typename OT>
__global__ void fold_mole(const float* __restrict__ w, const float* __restrict__ As,
                          const float* __restrict__ Bs, const float* __restrict__ Ae,
                          const float* __restrict__ Be, OT* __restrict__ out) {
  const int i = blockIdx.x;   // 512 (out dim)
  const int e = blockIdx.y;   // 8
  const int k = threadIdx.x;  // 512 (in dim)
  float acc = w[(long)k * NH + i];
#pragma unroll
  for (int r = 0; r < NR; ++r) acc += As[k * NR + r] * Bs[r * NH + i];
  const float* Aep = Ae + ((long)e * NH + k) * NR;
  const float* Bep = Be + (long)e * NR * NH + i;
#pragma unroll
  for (int r = 0; r < NR; ++r) acc += Aep[r] * Bep[(long)r * NH];
  out[((long)e * NH + i) * NH + k] = (OT)acc;
}

// ---- fold head_2 (out dim 1): w2f[e][k]
__global__ void fold_h2(const float* __restrict__ w, const float* __restrict__ As,
                        const float* __restrict__ Bs, const float* __restrict__ Ae,
                        const float* __restrict__ Be, float* __restrict__ out) {
  const int e = blockIdx.x, k = threadIdx.x;
  float acc = w[k];
#pragma unroll
  for (int r = 0; r < NR; ++r) acc += As[k * NR + r] * Bs[r];
#pragma unroll
  for (int r = 0; r < NR; ++r) acc += Ae[((long)e * NH + k) * NR + r] * Be[e * NR + r];
  out[e * NH + k] = acc;
}

// ---- pack conv weights [O][I][3] -> wp[dt][o][i] (f16)
__global__ void pack_conv(const float* __restrict__ cw, f16* __restrict__ wp) {
  const int o = blockIdx.x, i = threadIdx.x;
  const float* s = cw + ((long)o * NH + i) * 3;
#pragma unroll
  for (int dt = 0; dt < 3; ++dt)
    wp[((long)dt * NH + o) * NH + i] = (f16)s[dt];
}

// ---- fp32 obs -> fp16, written into padded ybuf rows 1..512 (aliased as obs buffer)
__global__ void cvt_obs(const float* __restrict__ in, f16* __restrict__ outp) {
  const int r = blockIdx.x;          // b*512 + t
  const int b = r >> 9, t = r & 511;
  const int c = threadIdx.x * 4;     // 128 threads x 4 elems
  const float4 v = *(const float4*)(in + (long)r * NH + c);
  f16x4 o; o[0] = (f16)v.x; o[1] = (f16)v.y; o[2] = (f16)v.z; o[3] = (f16)v.w;
  *(f16x4*)(outp + ((long)b * PADT + 1 + t) * NH + c) = o;
}

// ---- zero pad rows (row 0, row 513) of both padded buffers
__global__ void zero_pads(f16* __restrict__ h, f16* __restrict__ y) {
  const int b = blockIdx.x, t = threadIdx.x;  // 512
  const long s = (long)b * PADT * NH;
  h[s + t] = (f16)0; h[s + (long)513 * NH + t] = (f16)0;
  y[s + t] = (f16)0; y[s + (long)513 * NH + t] = (f16)0;
}

// ---------------- main NT GEMM with MFMA f16 ----------------
// C[m][n] = sum_a sum_k A[a][m][k] * B[a][n][k];  epilogue: +bias[n], leaky, f16 store.
// A rows contiguous in K (ld=512); B rows contiguous in K (ld=512).
template <int NACC, bool PSB>
__global__ __launch_bounds__(256, 2) void gemm_nt(
    const f16* __restrict__ A, long sA, int shiftA,
    const f16* __restrict__ Bm, long sBe, long sBacc,
    const float* __restrict__ bias,
    f16* __restrict__ O, long sO, int oRowOff,
    const int* __restrict__ eidx) {
  constexpr int BM = 128, BN = 128, BK = 64, LDK = 512;
  __shared__ __align__(16) f16 As[BM * BK];
  __shared__ __align__(16) f16 Bs[BN * BK];
  const int b = blockIdx.z;
  const int mt = blockIdx.x, nt = blockIdx.y;
  const int tid = threadIdx.x;
  const int wid = tid >> 6, lane = tid & 63;
  const int wm = wid >> 1, wn = wid & 1;
  const f16* Abase = A + (long)b * sA + (long)mt * BM * LDK;
  const f16* Bbase = Bm + (PSB ? (long)eidx[b] * sBe : 0) + (long)nt * BN * LDK;

  f32x4 acc[4][4] = {};

  const int srow = tid >> 3;  // staging: (i*256+tid)>>3 = i*32 + srow
  const int sc = tid & 7;

  for (int a = 0; a < NACC; ++a) {
    const f16* Aa = Abase + (long)a * shiftA;
    const f16* Ba = Bbase + (long)a * sBacc;
    for (int kt = 0; kt < LDK / BK; ++kt) {
      __syncthreads();  // previous compute done reading LDS
#pragma unroll
      for (int i = 0; i < 4; ++i) {
        const int row = i * 32 + srow;
        const int cs = sc ^ (row & 7);  // pre-swizzled global source => swizzled LDS, linear dest
        load_lds16(Aa + (long)row * LDK + kt * BK + cs * 8,
                   (char*)As + i * 4096 + wid * 1024);
        load_lds16(Ba + (long)row * LDK + kt * BK + cs * 8,
                   (char*)Bs + i * 4096 + wid * 1024);
      }
      __syncthreads();  // staged data visible (vmcnt drained before barrier)
#pragma unroll
      for (int kk = 0; kk < BK / 32; ++kk) {
        f16x8 af[4], bf[4];
#pragma unroll
        for (int mi = 0; mi < 4; ++mi) {
          const int row = wm * 64 + mi * 16 + (lane & 15);
          const int cc = (kk * 4 + (lane >> 4)) ^ (row & 7);
          af[mi] = *(const f16x8*)(As + row * BK + cc * 8);
        }
#pragma unroll
        for (int ni = 0; ni < 4; ++ni) {
          const int row = wn * 64 + ni * 16 + (lane & 15);
          const int cc = (kk * 4 + (lane >> 4)) ^ (row & 7);
          bf[ni] = *(const f16x8*)(Bs + row * BK + cc * 8);
        }
#pragma unroll
        for (int mi = 0; mi < 4; ++mi)
#pragma unroll
          for (int ni = 0; ni < 4; ++ni)
            acc[mi][ni] = __builtin_amdgcn_mfma_f32_16x16x32_f16(af[mi], bf[ni], acc[mi][ni], 0, 0, 0);
      }
    }
  }

  // epilogue: bias + leaky_relu(0.01) + f16 store (C/D map: col=lane&15, row=(lane>>4)*4+r)
  const int c0 = lane & 15, r0 = (lane >> 4) * 4;
#pragma unroll
  for (int ni = 0; ni < 4; ++ni) {
    const int gcol = nt * BN + wn * 64 + ni * 16 + c0;
    const float bv = bias[gcol];
#pragma unroll
    for (int mi = 0; mi < 4; ++mi) {
      const int grow = mt * BM + wm * 64 + mi * 16 + r0;
      f16* op = O + (long)b * sO + (long)(grow + oRowOff) * NH + gcol;
#pragma unroll
      for (int r = 0; r < 4; ++r) {
        float v = acc[mi][ni][r] + bv;
        v = v > 0.f ? v : 0.01f * v;
        op[(long)r * NH] = (f16)v;
      }
    }
  }
}

// ---- max over T (rows 1..512 of padded buffer) -> pooled[b][o] f32
__global__ void maxpool_kernel(const f16* __restrict__ y, float* __restrict__ pooled) {
  const int b = blockIdx.x, o = threadIdx.x;  // 512
  const f16* p = y + (long)b * PADT * NH + NH + o;
  float m = -3.0e38f;
  for (int t = 0; t < NT; ++t) m = fmaxf(m, (float)p[(long)t * NH]);
  pooled[b * NH + o] = m;
}

// ---- head_1: x1[b][o] = leaky(bias[o] + sum_k pooled[b][k] * W1T[e][o][k])
__global__ void head1_kernel(const float* __restrict__ pooled, const float* __restrict__ W,
                             const float* __restrict__ bias, const int* __restrict__ eidx,
                             float* __restrict__ x1) {
  const int b = blockIdx.x, o = threadIdx.x;  // 512
  __shared__ float xs[NH];
  xs[o] = pooled[b * NH + o];
  __syncthreads();
  const float* wrow = W + ((long)eidx[b] * NH + o) * NH;
  float acc = bias[o];
  for (int k = 0; k < NH; k += 4) {
    const float4 w4 = *(const float4*)(wrow + k);
    acc += xs[k] * w4.x + xs[k + 1] * w4.y + xs[k + 2] * w4.z + xs[k + 3] * w4.w;
  }
  x1[b * NH + o] = acc > 0.f ? acc : 0.01f * acc;
}

// ---- head_2: out[b] = b2 + sum_k x1[b][k] * w2f[e][k]
__global__ void head2_kernel(const float* __restrict__ x1, const float* __restrict__ w2f,
                             const float* __restrict__ b2, const int* __restrict__ eidx,
                             float* __restrict__ out) {
  const int b = blockIdx.x, t = threadIdx.x;  // 256
  const float* w = w2f + (long)eidx[b] * NH;
  const float* x = x1 + (long)b * NH;
  float acc = 0.f;
  for (int k = t; k < NH; k += 256) acc += x[k] * w[k];
  __shared__ float red[4];
  for (int off = 32; off; off >>= 1) acc += __shfl_down(acc, off, 64);
  if ((t & 63) == 0) red[t >> 6] = acc;
  __syncthreads();
  if (t == 0) out[b] = red[0] + red[1] + red[2] + red[3] + b2[0];
}

extern "C" void kernel_launch(void* const* d_in, const int* in_sizes, int n_in,
                              void* d_out, int out_size, void* d_ws, size_t ws_size,
                              hipStream_t stream) {
  const float* user_emb = (const float*)d_in[0];
  const float* obs   = (const float*)d_in[1];
  const float* gw1   = (const float*)d_in[2];
  const float* gb1   = (const float*)d_in[3];
  const float* gw2   = (const float*)d_in[4];
  const float* gb2   = (const float*)d_in[5];
  const float* op_w  = (const float*)d_in[6];
  const float* op_b  = (const float*)d_in[7];
  const float* op_As = (const float*)d_in[8];
  const float* op_Bs = (const float*)d_in[9];
  const float* op_Ae = (const float*)d_in[10];
  const float* op_Be = (const float*)d_in[11];
  const float* cw1   = (const float*)d_in[12];
  const float* cb1   = (const float*)d_in[13];
  const float* cw2   = (const float*)d_in[14];
  const float* cb2   = (const float*)d_in[15];
  const float* h1_w  = (const float*)d_in[16];
  const float* h1_b  = (const float*)d_in[17];
  const float* h1_As = (const float*)d_in[18];
  const float* h1_Bs = (const float*)d_in[19];
  const float* h1_Ae = (const float*)d_in[20];
  const float* h1_Be = (const float*)d_in[21];
  const float* h2_w  = (const float*)d_in[22];
  const float* h2_b  = (const float*)d_in[23];
  const float* h2_As = (const float*)d_in[24];
  const float* h2_Bs = (const float*)d_in[25];
  const float* h2_Ae = (const float*)d_in[26];
  const float* h2_Be = (const float*)d_in[27];
  float* out = (float*)d_out;

  char* ws = (char*)d_ws;
  size_t off = 0;
  auto carve = [&](size_t bytes) -> void* {
    void* p = ws + off;
    off += (bytes + 255) & ~(size_t)255;
    return p;
  };
  int*   eidx   = (int*)carve(NB * sizeof(int));
  f16*   WeT    = (f16*)carve((size_t)NE * NH * NH * sizeof(f16));      // 4 MB
  float* W1T    = (float*)carve((size_t)NE * NH * NH * sizeof(float));  // 8 MB
  float* w2f    = (float*)carve((size_t)NE * NH * sizeof(float));
  f16*   w1p    = (f16*)carve((size_t)3 * NH * NH * sizeof(f16));       // 1.5 MB
  f16*   w2p    = (f16*)carve((size_t)3 * NH * NH * sizeof(f16));
  float* pooled = (float*)carve((size_t)NB * NH * sizeof(float));
  float* x1     = (float*)carve((size_t)NB * NH * sizeof(float));
  f16*   hbuf   = (f16*)carve((size_t)NB * PADT * NH * sizeof(f16));    // 33.7 MB
  f16*   ybuf   = (f16*)carve((size_t)NB * PADT * NH * sizeof(f16));    // 33.7 MB
  // obs_h aliases ybuf rows 1..512 of each batch (dead once gemm1 has consumed it;
  // conv1 then overwrites those rows with its own output). Total ws ~82.5 MB.
  f16*   obs_h  = ybuf + NH;  // padded stride PADT*NH per batch
  (void)ws_size; (void)in_sizes; (void)n_in; (void)out_size;

  // -- prep (all tiny) --
  gating_kernel<<<NB, 128, 0, stream>>>(user_emb, gw1, gb1, gw2, gb2, eidx);
  fold_mole<f16><<<dim3(NH, NE), NH, 0, stream>>>(op_w, op_As, op_Bs, op_Ae, op_Be, WeT);
  fold_mole<float><<<dim3(NH, NE), NH, 0, stream>>>(h1_w, h1_As, h1_Bs, h1_Ae, h1_Be, W1T);
  fold_h2<<<NE, NH, 0, stream>>>(h2_w, h2_As, h2_Bs, h2_Ae, h2_Be, w2f);
  pack_conv<<<NH, NH, 0, stream>>>(cw1, w1p);
  pack_conv<<<NH, NH, 0, stream>>>(cw2, w2p);
  cvt_obs<<<NB * NT, 128, 0, stream>>>(obs, ybuf);
  zero_pads<<<NB, NH, 0, stream>>>(hbuf, ybuf);

  // -- heavy GEMMs --
  dim3 gg(4, 4, NB);
  // obs_proj: h[t][i] = leaky(obs[b] @ W_e + b), written to padded hbuf rows 1..512
  gemm_nt<1, true><<<gg, 256, 0, stream>>>(obs_h, (long)PADT * NH, 0,
                                           WeT, (long)NH * NH, 0,
                                           op_b, hbuf, (long)PADT * NH, 1, eidx);
  // conv1: y[t][o] = leaky(sum_dt sum_i h[t+dt-1][i] w1[o][i][dt] + cb1)
  gemm_nt<3, false><<<gg, 256, 0, stream>>>(hbuf, (long)PADT * NH, NH,
                                            w1p, 0, (long)NH * NH,
                                            cb1, ybuf, (long)PADT * NH, 1, eidx);
  // conv2 (writes back into hbuf; pads still zero)
  gemm_nt<3, false><<<gg, 256, 0, stream>>>(ybuf, (long)PADT * NH, NH,
                                            w2p, 0, (long)NH * NH,
                                            cb2, hbuf, (long)PADT * NH, 1, eidx);

  // -- tail --
  maxpool_kernel<<<NB, NH, 0, stream>>>(hbuf, pooled);
  head1_kernel<<<NB, NH, 0, stream>>>(pooled, W1T, h1_b, eidx, x1);
  head2_kernel<<<NB, 256, 0, stream>>>(x1, w2f, h2_b, eidx, out);
}

// Round 3
// 342.732 us; speedup vs baseline: 1.3698x; 1.3698x over previous
//
#include <hip/hip_runtime.h>
#include <cstdint>

typedef _Float16 f16;
typedef _Float16 f16x8 __attribute__((ext_vector_type(8)));
typedef _Float16 f16x4 __attribute__((ext_vector_type(4)));
typedef float f32x4 __attribute__((ext_vector_type(4)));

#define NB   64      // batch
#define NT   512     // T
#define NH   512     // HID == OBS_DIM == MLP_HID
#define NE   8
#define NR   8
#define PADT 514     // T + 2 pad rows

__device__ __forceinline__ void load_lds16(const void* g, void* l) {
  __builtin_amdgcn_global_load_lds(
      (const __attribute__((address_space(1))) uint32_t*)g,
      (__attribute__((address_space(3))) uint32_t*)l, 16, 0, 0);
}

// ordered-int atomic max on float (init must be -inf)
__device__ __forceinline__ void atomicMaxF(float* a, float v) {
  if (v >= 0.f) atomicMax((int*)a, __float_as_int(v));
  else          atomicMin((unsigned int*)a, __float_as_uint(v));
}

// ---------------- gating: relu(ue@gw1+gb1)@gw2+gb2 -> argmax -> eidx ----------
__global__ void gating_kernel(const float* __restrict__ ue, const float* __restrict__ gw1,
                              const float* __restrict__ gb1, const float* __restrict__ gw2,
                              const float* __restrict__ gb2, int* __restrict__ eidx) {
  const int b = blockIdx.x;
  __shared__ float ues[128];
  __shared__ float g1[128];
  __shared__ float zs[NE];
  const int j = threadIdx.x;  // 128
  ues[j] = ue[b * 128 + j];
  __syncthreads();
  float acc = gb1[j];
  for (int k = 0; k < 128; ++k) acc += ues[k] * gw1[k * 128 + j];
  g1[j] = fmaxf(acc, 0.f);
  __syncthreads();
  if (j < NE) {
    float z = gb2[j];
    for (int k = 0; k < 128; ++k) z += g1[k] * gw2[k * NE + j];
    zs[j] = z;
  }
  __syncthreads();
  if (j == 0) {
    int best = 0; float bz = zs[0];
    for (int e = 1; e < NE; ++e) if (zs[e] > bz) { bz = zs[e]; best = e; }
    eidx[b] = best;  // argmax(softmax(z/tau)) == argmax(z); rw is numerically one-hot
  }
}

// ---- fold MoLE weights: out[e][i][k] = w[k][i] + sum_r As[k][r]Bs[r][i] + Ae[e][k][r]Be[e][r][i]
template <typename OT>
__global__ void fold_mole(const float* __restrict__ w, const float* __restrict__ As,
                          const float* __restrict__ Bs, const float* __restrict__ Ae,
                          const float* __restrict__ Be, OT* __restrict__ out) {
  const int i = blockIdx.x;   // 512 (out dim)
  const int e = blockIdx.y;   // 8
  const int k = threadIdx.x;  // 512 (in dim)
  float acc = w[(long)k * NH + i];
#pragma unroll
  for (int r = 0; r < NR; ++r) acc += As[k * NR + r] * Bs[r * NH + i];
  const float* Aep = Ae + ((long)e * NH + k) * NR;
  const float* Bep = Be + (long)e * NR * NH + i;
#pragma unroll
  for (int r = 0; r < NR; ++r) acc += Aep[r] * Bep[(long)r * NH];
  out[((long)e * NH + i) * NH + k] = (OT)acc;
}

// ---- fold head_2 (out dim 1): w2f[e][k]
__global__ void fold_h2(const float* __restrict__ w, const float* __restrict__ As,
                        const float* __restrict__ Bs, const float* __restrict__ Ae,
                        const float* __restrict__ Be, float* __restrict__ out) {
  const int e = blockIdx.x, k = threadIdx.x;
  float acc = w[k];
#pragma unroll
  for (int r = 0; r < NR; ++r) acc += As[k * NR + r] * Bs[r];
#pragma unroll
  for (int r = 0; r < NR; ++r) acc += Ae[((long)e * NH + k) * NR + r] * Be[e * NR + r];
  out[e * NH + k] = acc;
}

// ---- pack conv weights [O][I][3] -> wp[dt][o][i] (f16)
__global__ void pack_conv(const float* __restrict__ cw, f16* __restrict__ wp) {
  const int o = blockIdx.x, i = threadIdx.x;
  const float* s = cw + ((long)o * NH + i) * 3;
#pragma unroll
  for (int dt = 0; dt < 3; ++dt)
    wp[((long)dt * NH + o) * NH + i] = (f16)s[dt];
}

// ---- fp32 obs -> fp16, written into padded ybuf rows 1..512 (aliased as obs buffer)
__global__ void cvt_obs(const float* __restrict__ in, f16* __restrict__ outp) {
  const int r = blockIdx.x;          // b*512 + t
  const int b = r >> 9, t = r & 511;
  const int c = threadIdx.x * 4;     // 128 threads x 4 elems
  const float4 v = *(const float4*)(in + (long)r * NH + c);
  f16x4 o; o[0] = (f16)v.x; o[1] = (f16)v.y; o[2] = (f16)v.z; o[3] = (f16)v.w;
  *(f16x4*)(outp + ((long)b * PADT + 1 + t) * NH + c) = o;
}

// ---- zero pad rows (row 0, row 513) of both padded buffers + init pooled to -inf
__global__ void zero_pads(f16* __restrict__ h, f16* __restrict__ y, float* __restrict__ pooled) {
  const int b = blockIdx.x, t = threadIdx.x;  // 512
  const long s = (long)b * PADT * NH;
  h[s + t] = (f16)0; h[s + (long)513 * NH + t] = (f16)0;
  y[s + t] = (f16)0; y[s + (long)513 * NH + t] = (f16)0;
  pooled[b * NH + t] = -__builtin_inff();
}

// ---------------- main NT GEMM with MFMA f16 ----------------
// C[m][n] = sum_a sum_k A[a][m][k] * B[a][n][k];  epilogue: +bias[n], leaky,
// then either f16 store (POOL=false) or per-column max -> atomicMaxF (POOL=true).
template <int NACC, bool PSB, bool POOL>
__global__ __launch_bounds__(256, 2) void gemm_nt(
    const f16* __restrict__ A, long sA, int shiftA,
    const f16* __restrict__ Bm, long sBe, long sBacc,
    const float* __restrict__ bias,
    f16* __restrict__ O, long sO, int oRowOff,
    float* __restrict__ pooledOut,
    const int* __restrict__ eidx) {
  constexpr int BM = 128, BN = 128, BK = 64, LDK = 512;
  __shared__ __align__(16) f16 As[BM * BK];
  __shared__ __align__(16) f16 Bs[BN * BK];
  const int b = blockIdx.z;
  const int mt = blockIdx.x, nt = blockIdx.y;
  const int tid = threadIdx.x;
  const int wid = tid >> 6, lane = tid & 63;
  const int wm = wid >> 1, wn = wid & 1;
  const f16* Abase = A + (long)b * sA + (long)mt * BM * LDK;
  const f16* Bbase = Bm + (PSB ? (long)eidx[b] * sBe : 0) + (long)nt * BN * LDK;

  f32x4 acc[4][4] = {};

  const int srow = tid >> 3;  // staging: (i*256+tid)>>3 = i*32 + srow
  const int sc = tid & 7;

  for (int a = 0; a < NACC; ++a) {
    const f16* Aa = Abase + (long)a * shiftA;
    const f16* Ba = Bbase + (long)a * sBacc;
    for (int kt = 0; kt < LDK / BK; ++kt) {
      __syncthreads();  // previous compute done reading LDS
#pragma unroll
      for (int i = 0; i < 4; ++i) {
        const int row = i * 32 + srow;
        const int cs = sc ^ (row & 7);  // pre-swizzled global source => swizzled LDS, linear dest
        load_lds16(Aa + (long)row * LDK + kt * BK + cs * 8,
                   (char*)As + i * 4096 + wid * 1024);
        load_lds16(Ba + (long)row * LDK + kt * BK + cs * 8,
                   (char*)Bs + i * 4096 + wid * 1024);
      }
      __syncthreads();  // staged data visible (vmcnt drained before barrier)
#pragma unroll
      for (int kk = 0; kk < BK / 32; ++kk) {
        f16x8 af[4], bf[4];
#pragma unroll
        for (int mi = 0; mi < 4; ++mi) {
          const int row = wm * 64 + mi * 16 + (lane & 15);
          const int cc = (kk * 4 + (lane >> 4)) ^ (row & 7);
          af[mi] = *(const f16x8*)(As + row * BK + cc * 8);
        }
#pragma unroll
        for (int ni = 0; ni < 4; ++ni) {
          const int row = wn * 64 + ni * 16 + (lane & 15);
          const int cc = (kk * 4 + (lane >> 4)) ^ (row & 7);
          bf[ni] = *(const f16x8*)(Bs + row * BK + cc * 8);
        }
#pragma unroll
        for (int mi = 0; mi < 4; ++mi)
#pragma unroll
          for (int ni = 0; ni < 4; ++ni)
            acc[mi][ni] = __builtin_amdgcn_mfma_f32_16x16x32_f16(af[mi], bf[ni], acc[mi][ni], 0, 0, 0);
      }
    }
  }

  // epilogue (C/D map: col=lane&15, row=(lane>>4)*4+r)
  const int c0 = lane & 15, r0 = (lane >> 4) * 4;
  if (POOL) {
    // bias + leaky + max over this block's 128 rows per column, atomic into pooled
#pragma unroll
    for (int ni = 0; ni < 4; ++ni) {
      const int gcol = nt * BN + wn * 64 + ni * 16 + c0;
      const float bv = bias[gcol];
      float m = -3.0e38f;
#pragma unroll
      for (int mi = 0; mi < 4; ++mi)
#pragma unroll
        for (int r = 0; r < 4; ++r) {
          float v = acc[mi][ni][r] + bv;
          v = v > 0.f ? v : 0.01f * v;
          m = fmaxf(m, v);
        }
      // rows differ across lane>>4 groups (xor 16, 32) and across wm warps (atomic handles)
      m = fmaxf(m, __shfl_xor(m, 16, 64));
      m = fmaxf(m, __shfl_xor(m, 32, 64));
      if ((lane >> 4) == 0) atomicMaxF(pooledOut + (long)b * NH + gcol, m);
    }
  } else {
#pragma unroll
    for (int ni = 0; ni < 4; ++ni) {
      const int gcol = nt * BN + wn * 64 + ni * 16 + c0;
      const float bv = bias[gcol];
#pragma unroll
      for (int mi = 0; mi < 4; ++mi) {
        const int grow = mt * BM + wm * 64 + mi * 16 + r0;
        f16* op = O + (long)b * sO + (long)(grow + oRowOff) * NH + gcol;
#pragma unroll
        for (int r = 0; r < 4; ++r) {
          float v = acc[mi][ni][r] + bv;
          v = v > 0.f ? v : 0.01f * v;
          op[(long)r * NH] = (f16)v;
        }
      }
    }
  }
}

// ---- head_1: x1[b][o] = leaky(bias[o] + sum_k pooled[b][k] * W1T[e][o][k]), k split 4-way
__global__ void head1_kernel(const float* __restrict__ pooled, const float* __restrict__ W,
                             const float* __restrict__ bias, const int* __restrict__ eidx,
                             float* __restrict__ x1) {
  const int b = blockIdx.x, oc = blockIdx.y;
  const int tid = threadIdx.x;        // 512
  const int ol = tid & 127;           // local o within 128-chunk
  const int o  = oc * 128 + ol;
  const int ks = tid >> 7;            // k-slice 0..3
  __shared__ float xs[NH];
  __shared__ float red[4][128];
  xs[tid] = pooled[b * NH + tid];
  __syncthreads();
  const float* wrow = W + ((long)eidx[b] * NH + o) * NH + ks * 128;
  const float* xp = xs + ks * 128;
  float acc = 0.f;
#pragma unroll 8
  for (int k = 0; k < 128; k += 4) {
    const float4 w4 = *(const float4*)(wrow + k);
    acc += xp[k] * w4.x + xp[k + 1] * w4.y + xp[k + 2] * w4.z + xp[k + 3] * w4.w;
  }
  red[ks][ol] = acc;
  __syncthreads();
  if (tid < 128) {
    const int oo = oc * 128 + tid;
    float v = red[0][tid] + red[1][tid] + red[2][tid] + red[3][tid] + bias[oo];
    x1[b * NH + oo] = v > 0.f ? v : 0.01f * v;
  }
}

// ---- head_2: out[b] = b2 + sum_k x1[b][k] * w2f[e][k]
__global__ void head2_kernel(const float* __restrict__ x1, const float* __restrict__ w2f,
                             const float* __restrict__ b2, const int* __restrict__ eidx,
                             float* __restrict__ out) {
  const int b = blockIdx.x, t = threadIdx.x;  // 256
  const float* w = w2f + (long)eidx[b] * NH;
  const float* x = x1 + (long)b * NH;
  float acc = 0.f;
  for (int k = t; k < NH; k += 256) acc += x[k] * w[k];
  __shared__ float red[4];
  for (int off = 32; off; off >>= 1) acc += __shfl_down(acc, off, 64);
  if ((t & 63) == 0) red[t >> 6] = acc;
  __syncthreads();
  if (t == 0) out[b] = red[0] + red[1] + red[2] + red[3] + b2[0];
}

extern "C" void kernel_launch(void* const* d_in, const int* in_sizes, int n_in,
                              void* d_out, int out_size, void* d_ws, size_t ws_size,
                              hipStream_t stream) {
  const float* user_emb = (const float*)d_in[0];
  const float* obs   = (const float*)d_in[1];
  const float* gw1   = (const float*)d_in[2];
  const float* gb1   = (const float*)d_in[3];
  const float* gw2   = (const float*)d_in[4];
  const float* gb2   = (const float*)d_in[5];
  const float* op_w  = (const float*)d_in[6];
  const float* op_b  = (const float*)d_in[7];
  const float* op_As = (const float*)d_in[8];
  const float* op_Bs = (const float*)d_in[9];
  const float* op_Ae = (const float*)d_in[10];
  const float* op_Be = (const float*)d_in[11];
  const float* cw1   = (const float*)d_in[12];
  const float* cb1   = (const float*)d_in[13];
  const float* cw2   = (const float*)d_in[14];
  const float* cb2   = (const float*)d_in[15];
  const float* h1_w  = (const float*)d_in[16];
  const float* h1_b  = (const float*)d_in[17];
  const float* h1_As = (const float*)d_in[18];
  const float* h1_Bs = (const float*)d_in[19];
  const float* h1_Ae = (const float*)d_in[20];
  const float* h1_Be = (const float*)d_in[21];
  const float* h2_w  = (const float*)d_in[22];
  const float* h2_b  = (const float*)d_in[23];
  const float* h2_As = (const float*)d_in[24];
  const float* h2_Bs = (const float*)d_in[25];
  const float* h2_Ae = (const float*)d_in[26];
  const float* h2_Be = (const float*)d_in[27];
  float* out = (float*)d_out;

  char* ws = (char*)d_ws;
  size_t off = 0;
  auto carve = [&](size_t bytes) -> void* {
    void* p = ws + off;
    off += (bytes + 255) & ~(size_t)255;
    return p;
  };
  int*   eidx   = (int*)carve(NB * sizeof(int));
  f16*   WeT    = (f16*)carve((size_t)NE * NH * NH * sizeof(f16));      // 4 MB
  float* W1T    = (float*)carve((size_t)NE * NH * NH * sizeof(float));  // 8 MB
  float* w2f    = (float*)carve((size_t)NE * NH * sizeof(float));
  f16*   w1p    = (f16*)carve((size_t)3 * NH * NH * sizeof(f16));       // 1.5 MB
  f16*   w2p    = (f16*)carve((size_t)3 * NH * NH * sizeof(f16));
  float* pooled = (float*)carve((size_t)NB * NH * sizeof(float));
  float* x1     = (float*)carve((size_t)NB * NH * sizeof(float));
  f16*   hbuf   = (f16*)carve((size_t)NB * PADT * NH * sizeof(f16));    // 33.7 MB
  f16*   ybuf   = (f16*)carve((size_t)NB * PADT * NH * sizeof(f16));    // 33.7 MB
  // obs_h aliases ybuf rows 1..512 of each batch (dead once gemm1 has consumed it;
  // conv1 then overwrites those rows with its own output). Total ws ~82.5 MB.
  f16*   obs_h  = ybuf + NH;  // padded stride PADT*NH per batch
  (void)ws_size; (void)in_sizes; (void)n_in; (void)out_size;

  // -- prep (all tiny) --
  gating_kernel<<<NB, 128, 0, stream>>>(user_emb, gw1, gb1, gw2, gb2, eidx);
  fold_mole<f16><<<dim3(NH, NE), NH, 0, stream>>>(op_w, op_As, op_Bs, op_Ae, op_Be, WeT);
  fold_mole<float><<<dim3(NH, NE), NH, 0, stream>>>(h1_w, h1_As, h1_Bs, h1_Ae, h1_Be, W1T);
  fold_h2<<<NE, NH, 0, stream>>>(h2_w, h2_As, h2_Bs, h2_Ae, h2_Be, w2f);
  pack_conv<<<NH, NH, 0, stream>>>(cw1, w1p);
  pack_conv<<<NH, NH, 0, stream>>>(cw2, w2p);
  cvt_obs<<<NB * NT, 128, 0, stream>>>(obs, ybuf);
  zero_pads<<<NB, NH, 0, stream>>>(hbuf, ybuf, pooled);

  // -- heavy GEMMs --
  dim3 gg(4, 4, NB);
  // obs_proj: h[t][i] = leaky(obs[b] @ W_e + b), written to padded hbuf rows 1..512
  gemm_nt<1, true, false><<<gg, 256, 0, stream>>>(obs_h, (long)PADT * NH, 0,
                                                  WeT, (long)NH * NH, 0,
                                                  op_b, hbuf, (long)PADT * NH, 1,
                                                  nullptr, eidx);
  // conv1: y[t][o] = leaky(sum_dt sum_i h[t+dt-1][i] w1[o][i][dt] + cb1)
  gemm_nt<3, false, false><<<gg, 256, 0, stream>>>(hbuf, (long)PADT * NH, NH,
                                                   w1p, 0, (long)NH * NH,
                                                   cb1, ybuf, (long)PADT * NH, 1,
                                                   nullptr, eidx);
  // conv2 fused with max-pool: no output store, per-column max -> pooled
  gemm_nt<3, false, true><<<gg, 256, 0, stream>>>(ybuf, (long)PADT * NH, NH,
                                                  w2p, 0, (long)NH * NH,
                                                  cb2, nullptr, 0, 0,
                                                  pooled, eidx);

  // -- tail --
  head1_kernel<<<dim3(NB, 4), 512, 0, stream>>>(pooled, W1T, h1_b, eidx, x1);
  head2_kernel<<<NB, 256, 0, stream>>>(x1, w2f, h2_b, eidx, out);
}

// Round 4
// 319.052 us; speedup vs baseline: 1.4715x; 1.0742x over previous
//
#include <hip/hip_runtime.h>
#include <cstdint>

typedef _Float16 f16;
typedef _Float16 f16x8 __attribute__((ext_vector_type(8)));
typedef float f32x4 __attribute__((ext_vector_type(4)));

#define NB   64      // batch
#define NT   512     // T
#define NH   512     // HID == OBS_DIM == MLP_HID
#define NE   8
#define NR   8
#define PADT 514     // T + 2 pad rows

__device__ __forceinline__ void load_lds16(const void* g, void* l) {
  __builtin_amdgcn_global_load_lds(
      (const __attribute__((address_space(1))) uint32_t*)g,
      (__attribute__((address_space(3))) uint32_t*)l, 16, 0, 0);
}

// ordered-int atomic max on float (init must be -inf)
__device__ __forceinline__ void atomicMaxF(float* a, float v) {
  if (v >= 0.f) atomicMax((int*)a, __float_as_int(v));
  else          atomicMin((unsigned int*)a, __float_as_uint(v));
}

// ================= fused prep: gating | fold WeT | fold W1T | fold h2 | pack x2 | pads =================
// block ranges: [0,64) gating, [64,4160) fold WeT(f16), [4160,8256) fold W1T(f32),
// [8256,8264) fold_h2, [8264,8776) pack cw1, [8776,9288) pack cw2, [9288,9352) pads+pooled
#define PREP_BLOCKS 9352
__global__ __launch_bounds__(512) void prep_kernel(
    const float* __restrict__ ue, const float* __restrict__ gw1, const float* __restrict__ gb1,
    const float* __restrict__ gw2, const float* __restrict__ gb2,
    const float* __restrict__ op_w, const float* __restrict__ op_As, const float* __restrict__ op_Bs,
    const float* __restrict__ op_Ae, const float* __restrict__ op_Be,
    const float* __restrict__ h1_w, const float* __restrict__ h1_As, const float* __restrict__ h1_Bs,
    const float* __restrict__ h1_Ae, const float* __restrict__ h1_Be,
    const float* __restrict__ h2_w, const float* __restrict__ h2_As, const float* __restrict__ h2_Bs,
    const float* __restrict__ h2_Ae, const float* __restrict__ h2_Be,
    const float* __restrict__ cw1, const float* __restrict__ cw2,
    int* __restrict__ eidx, f16* __restrict__ WeT, float* __restrict__ W1T,
    float* __restrict__ w2f, f16* __restrict__ w1p, f16* __restrict__ w2p,
    f16* __restrict__ hbuf, f16* __restrict__ ybuf, float* __restrict__ pooled) {
  const int blk = blockIdx.x;
  const int tid = threadIdx.x;
  __shared__ float sbufA[128];
  __shared__ float sbufB[128];
  __shared__ float zs[NE];

  if (blk < 64) {                       // ---- gating (b = blk) ----
    const int b = blk;
    if (tid < 128) sbufA[tid] = ue[b * 128 + tid];
    __syncthreads();
    if (tid < 128) {
      float acc = gb1[tid];
      for (int k = 0; k < 128; ++k) acc += sbufA[k] * gw1[k * 128 + tid];
      sbufB[tid] = fmaxf(acc, 0.f);
    }
    __syncthreads();
    if (tid < NE) {
      float z = gb2[tid];
      for (int k = 0; k < 128; ++k) z += sbufB[k] * gw2[k * NE + tid];
      zs[tid] = z;
    }
    __syncthreads();
    if (tid == 0) {
      int best = 0; float bz = zs[0];
      for (int e = 1; e < NE; ++e) if (zs[e] > bz) { bz = zs[e]; best = e; }
      eidx[b] = best;  // argmax(softmax(z/tau)) == argmax(z); rw numerically one-hot
    }
  } else if (blk < 64 + 4096) {         // ---- fold obs_proj -> WeT[e][i][k] f16 ----
    const int q = blk - 64;
    const int i = q & 511, e = q >> 9, k = tid;
    float acc = op_w[(long)k * NH + i];
#pragma unroll
    for (int r = 0; r < NR; ++r) acc += op_As[k * NR + r] * op_Bs[r * NH + i];
    const float* Aep = op_Ae + ((long)e * NH + k) * NR;
    const float* Bep = op_Be + (long)e * NR * NH + i;
#pragma unroll
    for (int r = 0; r < NR; ++r) acc += Aep[r] * Bep[(long)r * NH];
    WeT[((long)e * NH + i) * NH + k] = (f16)acc;
  } else if (blk < 4160 + 4096) {       // ---- fold head1 -> W1T[e][i][k] f32 ----
    const int q = blk - 4160;
    const int i = q & 511, e = q >> 9, k = tid;
    float acc = h1_w[(long)k * NH + i];
#pragma unroll
    for (int r = 0; r < NR; ++r) acc += h1_As[k * NR + r] * h1_Bs[r * NH + i];
    const float* Aep = h1_Ae + ((long)e * NH + k) * NR;
    const float* Bep = h1_Be + (long)e * NR * NH + i;
#pragma unroll
    for (int r = 0; r < NR; ++r) acc += Aep[r] * Bep[(long)r * NH];
    W1T[((long)e * NH + i) * NH + k] = acc;
  } else if (blk < 8256 + 8) {          // ---- fold head2 -> w2f[e][k] ----
    const int e = blk - 8256, k = tid;
    float acc = h2_w[k];
#pragma unroll
    for (int r = 0; r < NR; ++r) acc += h2_As[k * NR + r] * h2_Bs[r];
#pragma unroll
    for (int r = 0; r < NR; ++r) acc += h2_Ae[((long)e * NH + k) * NR + r] * h2_Be[e * NR + r];
    w2f[e * NH + k] = acc;
  } else if (blk < 8264 + 512) {        // ---- pack cw1 [O][I][3] -> w1p[dt][o][i] ----
    const int o = blk - 8264, i = tid;
    const float* s = cw1 + ((long)o * NH + i) * 3;
#pragma unroll
    for (int dt = 0; dt < 3; ++dt) w1p[((long)dt * NH + o) * NH + i] = (f16)s[dt];
  } else if (blk < 8776 + 512) {        // ---- pack cw2 ----
    const int o = blk - 8776, i = tid;
    const float* s = cw2 + ((long)o * NH + i) * 3;
#pragma unroll
    for (int dt = 0; dt < 3; ++dt) w2p[((long)dt * NH + o) * NH + i] = (f16)s[dt];
  } else {                              // ---- zero pad rows + pooled=-inf ----
    const int b = blk - 9288, t = tid;
    const long s = (long)b * PADT * NH;
    hbuf[s + t] = (f16)0; hbuf[s + (long)513 * NH + t] = (f16)0;
    ybuf[s + t] = (f16)0; ybuf[s + (long)513 * NH + t] = (f16)0;
    pooled[b * NH + t] = -__builtin_inff();
  }
}

// ================= main NT GEMM, MFMA f16, kt-outer with NDT dt-panels resident =================
// C[m][n] = sum_dt sum_k A[mt*128+m+dt][k] * B_dt[n][k]   (NDT=3: conv, A padded, halo staged)
//           or            A[mt*128+m][k]  * B[n][k]       (NDT=1: obs_proj, A from f32 if F32A)
// epilogue: +bias[n], leaky(0.01), then f16 store (POOL=0) or column-max -> atomicMaxF (POOL=1).
template <int NDT, bool F32A, bool PSB, bool POOL>
__global__ __launch_bounds__(256, 2) void fgemm(
    const f16* __restrict__ A, const float* __restrict__ A32, long sA,
    const f16* __restrict__ Bm, long sBe, long sBacc,
    const float* __restrict__ bias,
    f16* __restrict__ O, long sO, int oRowOff,
    float* __restrict__ pooledOut,
    const int* __restrict__ eidx) {
  constexpr int BK = 64, LDK = 512;
  constexpr int ASLOTS = (NDT == 3) ? 132 : 128;   // 130 used (128 + 2 halo) for conv
  constexpr int SOFF = (NDT == 3) ? 1 : 0;
  __shared__ __align__(16) f16 A_lds[ASLOTS * BK];
  __shared__ __align__(16) f16 B_lds[NDT * 128 * BK];
  const int b = blockIdx.z;
  const int mt = blockIdx.x, nt = blockIdx.y;
  const int tid = threadIdx.x;
  const int wid = tid >> 6, lane = tid & 63;
  const int wm = wid >> 1, wn = wid & 1;
  const f16* Ab = F32A ? nullptr : (A + (long)b * sA + (long)mt * 128 * LDK);
  const float* A32b = F32A ? (A32 + (long)b * sA + (long)mt * 128 * LDK) : nullptr;
  const f16* Bb = Bm + (PSB ? (long)eidx[b] * sBe : 0) + (long)nt * 128 * LDK;

  f32x4 acc[4][4] = {};

  for (int kt = 0; kt < LDK / BK; ++kt) {
    __syncthreads();  // previous compute done reading LDS
    // ---- stage B panels (global_load_lds, pre-swizzled source) ----
#pragma unroll
    for (int d = 0; d < NDT; ++d)
#pragma unroll
      for (int j = 0; j < 4; ++j) {
        const int row = j * 32 + (tid >> 3);
        const int cs = (tid & 7) ^ (row & 7);
        load_lds16(Bb + (long)d * sBacc + (long)row * LDK + kt * BK + cs * 8,
                   (char*)B_lds + d * 16384 + j * 4096 + wid * 1024);
      }
    // ---- stage A tile ----
    if (F32A) {
      // f32 -> f16 reg-staged, swizzled ds_write (kills the separate cvt pass)
#pragma unroll
      for (int i = 0; i < 4; ++i) {
        const int slot = i * 32 + (tid >> 3);
        const float* s = A32b + (long)slot * LDK + kt * BK + (tid & 7) * 8;
        const float4 v0 = *(const float4*)s;
        const float4 v1 = *(const float4*)(s + 4);
        f16x8 h;
        h[0] = (f16)v0.x; h[1] = (f16)v0.y; h[2] = (f16)v0.z; h[3] = (f16)v0.w;
        h[4] = (f16)v1.x; h[5] = (f16)v1.y; h[6] = (f16)v1.z; h[7] = (f16)v1.w;
        *(f16x8*)((char*)A_lds + slot * 128 + (((tid & 7) ^ (slot & 7)) * 16)) = h;
      }
    } else {
#pragma unroll
      for (int i = 0; i < 4; ++i) {
        const int slot = SOFF + i * 32 + (tid >> 3);
        const int cs = (tid & 7) ^ (slot & 7);
        load_lds16(Ab + (long)slot * LDK + kt * BK + cs * 8,
                   (char*)A_lds + SOFF * 128 + i * 4096 + wid * 1024);
      }
      if (NDT == 3) {
        // halo slots 0 and 129 (2 rows): exec-safe reg round-trip by 16 threads
        if (tid < 16) {
          const int hs = (tid < 8) ? 0 : 129;
          const int c8 = tid & 7;
          const int cs = c8 ^ (hs & 7);
          const f16x8 h = *(const f16x8*)(Ab + (long)hs * LDK + kt * BK + cs * 8);
          *(f16x8*)((char*)A_lds + hs * 128 + c8 * 16) = h;
        }
      }
    }
    __syncthreads();  // staged data visible (vmcnt+lgkmcnt drained before barrier)
    // ---- compute: NDT x 2kk x 16 MFMA ----
#pragma unroll
    for (int kk = 0; kk < BK / 32; ++kk)
#pragma unroll
      for (int d = 0; d < NDT; ++d) {
        f16x8 af[4], bf[4];
#pragma unroll
        for (int mi = 0; mi < 4; ++mi) {
          const int slot = wm * 64 + mi * 16 + (lane & 15) + (NDT == 3 ? d : 0);
          const int cc = (kk * 4 + (lane >> 4)) ^ (slot & 7);
          af[mi] = *(const f16x8*)(A_lds + slot * BK + cc * 8);
        }
#pragma unroll
        for (int ni = 0; ni < 4; ++ni) {
          const int row = wn * 64 + ni * 16 + (lane & 15);
          const int cc = (kk * 4 + (lane >> 4)) ^ (row & 7);
          bf[ni] = *(const f16x8*)(B_lds + d * 128 * BK + row * BK + cc * 8);
        }
#pragma unroll
        for (int mi = 0; mi < 4; ++mi)
#pragma unroll
          for (int ni = 0; ni < 4; ++ni)
            acc[mi][ni] = __builtin_amdgcn_mfma_f32_16x16x32_f16(af[mi], bf[ni], acc[mi][ni], 0, 0, 0);
      }
  }

  // ---- epilogue (C/D map: col=lane&15, row=(lane>>4)*4+r) ----
  const int c0 = lane & 15, r0 = (lane >> 4) * 4;
  if (POOL) {
#pragma unroll
    for (int ni = 0; ni < 4; ++ni) {
      const int gcol = nt * 128 + wn * 64 + ni * 16 + c0;
      const float bv = bias[gcol];
      float m = -3.0e38f;
#pragma unroll
      for (int mi = 0; mi < 4; ++mi)
#pragma unroll
        for (int r = 0; r < 4; ++r) {
          float v = acc[mi][ni][r] + bv;
          v = v > 0.f ? v : 0.01f * v;
          m = fmaxf(m, v);
        }
      m = fmaxf(m, __shfl_xor(m, 16, 64));
      m = fmaxf(m, __shfl_xor(m, 32, 64));
      if ((lane >> 4) == 0) atomicMaxF(pooledOut + (long)b * NH + gcol, m);
    }
  } else {
#pragma unroll
    for (int ni = 0; ni < 4; ++ni) {
      const int gcol = nt * 128 + wn * 64 + ni * 16 + c0;
      const float bv = bias[gcol];
#pragma unroll
      for (int mi = 0; mi < 4; ++mi) {
        const int grow = mt * 128 + wm * 64 + mi * 16 + r0;
        f16* op = O + (long)b * sO + (long)(grow + oRowOff) * NH + gcol;
#pragma unroll
        for (int r = 0; r < 4; ++r) {
          float v = acc[mi][ni][r] + bv;
          v = v > 0.f ? v : 0.01f * v;
          op[(long)r * NH] = (f16)v;
        }
      }
    }
  }
}

// ---- head_1: x1[b][o] = leaky(bias[o] + sum_k pooled[b][k] * W1T[e][o][k]), k split 4-way
__global__ void head1_kernel(const float* __restrict__ pooled, const float* __restrict__ W,
                             const float* __restrict__ bias, const int* __restrict__ eidx,
                             float* __restrict__ x1) {
  const int b = blockIdx.x, oc = blockIdx.y;
  const int tid = threadIdx.x;        // 512
  const int ol = tid & 127;
  const int o  = oc * 128 + ol;
  const int ks = tid >> 7;            // k-slice 0..3
  __shared__ float xs[NH];
  __shared__ float red[4][128];
  xs[tid] = pooled[b * NH + tid];
  __syncthreads();
  const float* wrow = W + ((long)eidx[b] * NH + o) * NH + ks * 128;
  const float* xp = xs + ks * 128;
  float acc = 0.f;
#pragma unroll 8
  for (int k = 0; k < 128; k += 4) {
    const float4 w4 = *(const float4*)(wrow + k);
    acc += xp[k] * w4.x + xp[k + 1] * w4.y + xp[k + 2] * w4.z + xp[k + 3] * w4.w;
  }
  red[ks][ol] = acc;
  __syncthreads();
  if (tid < 128) {
    const int oo = oc * 128 + tid;
    float v = red[0][tid] + red[1][tid] + red[2][tid] + red[3][tid] + bias[oo];
    x1[b * NH + oo] = v > 0.f ? v : 0.01f * v;
  }
}

// ---- head_2: out[b] = b2 + sum_k x1[b][k] * w2f[e][k]
__global__ void head2_kernel(const float* __restrict__ x1, const float* __restrict__ w2f,
                             const float* __restrict__ b2, const int* __restrict__ eidx,
                             float* __restrict__ out) {
  const int b = blockIdx.x, t = threadIdx.x;  // 256
  const float* w = w2f + (long)eidx[b] * NH;
  const float* x = x1 + (long)b * NH;
  float acc = 0.f;
  for (int k = t; k < NH; k += 256) acc += x[k] * w[k];
  __shared__ float red[4];
  for (int off = 32; off; off >>= 1) acc += __shfl_down(acc, off, 64);
  if ((t & 63) == 0) red[t >> 6] = acc;
  __syncthreads();
  if (t == 0) out[b] = red[0] + red[1] + red[2] + red[3] + b2[0];
}

extern "C" void kernel_launch(void* const* d_in, const int* in_sizes, int n_in,
                              void* d_out, int out_size, void* d_ws, size_t ws_size,
                              hipStream_t stream) {
  const float* user_emb = (const float*)d_in[0];
  const float* obs   = (const float*)d_in[1];
  const float* gw1   = (const float*)d_in[2];
  const float* gb1   = (const float*)d_in[3];
  const float* gw2   = (const float*)d_in[4];
  const float* gb2   = (const float*)d_in[5];
  const float* op_w  = (const float*)d_in[6];
  const float* op_b  = (const float*)d_in[7];
  const float* op_As = (const float*)d_in[8];
  const float* op_Bs = (const float*)d_in[9];
  const float* op_Ae = (const float*)d_in[10];
  const float* op_Be = (const float*)d_in[11];
  const float* cw1   = (const float*)d_in[12];
  const float* cb1   = (const float*)d_in[13];
  const float* cw2   = (const float*)d_in[14];
  const float* cb2   = (const float*)d_in[15];
  const float* h1_w  = (const float*)d_in[16];
  const float* h1_b  = (const float*)d_in[17];
  const float* h1_As = (const float*)d_in[18];
  const float* h1_Bs = (const float*)d_in[19];
  const float* h1_Ae = (const float*)d_in[20];
  const float* h1_Be = (const float*)d_in[21];
  const float* h2_w  = (const float*)d_in[22];
  const float* h2_b  = (const float*)d_in[23];
  const float* h2_As = (const float*)d_in[24];
  const float* h2_Bs = (const float*)d_in[25];
  const float* h2_Ae = (const float*)d_in[26];
  const float* h2_Be = (const float*)d_in[27];
  float* out = (float*)d_out;

  char* ws = (char*)d_ws;
  size_t off = 0;
  auto carve = [&](size_t bytes) -> void* {
    void* p = ws + off;
    off += (bytes + 255) & ~(size_t)255;
    return p;
  };
  int*   eidx   = (int*)carve(NB * sizeof(int));
  f16*   WeT    = (f16*)carve((size_t)NE * NH * NH * sizeof(f16));      // 4 MB
  float* W1T    = (float*)carve((size_t)NE * NH * NH * sizeof(float));  // 8 MB
  float* w2f    = (float*)carve((size_t)NE * NH * sizeof(float));
  f16*   w1p    = (f16*)carve((size_t)3 * NH * NH * sizeof(f16));       // 1.5 MB
  f16*   w2p    = (f16*)carve((size_t)3 * NH * NH * sizeof(f16));
  float* pooled = (float*)carve((size_t)NB * NH * sizeof(float));
  float* x1     = (float*)carve((size_t)NB * NH * sizeof(float));
  f16*   hbuf   = (f16*)carve((size_t)NB * PADT * NH * sizeof(f16));    // 33.7 MB
  f16*   ybuf   = (f16*)carve((size_t)NB * PADT * NH * sizeof(f16));    // 33.7 MB
  (void)ws_size; (void)in_sizes; (void)n_in; (void)out_size;

  // -- fused prep (1 launch replaces 8) --
  prep_kernel<<<PREP_BLOCKS, 512, 0, stream>>>(
      user_emb, gw1, gb1, gw2, gb2,
      op_w, op_As, op_Bs, op_Ae, op_Be,
      h1_w, h1_As, h1_Bs, h1_Ae, h1_Be,
      h2_w, h2_As, h2_Bs, h2_Ae, h2_Be,
      cw1, cw2,
      eidx, WeT, W1T, w2f, w1p, w2p, hbuf, ybuf, pooled);

  // -- heavy GEMMs --
  dim3 gg(4, 4, NB);
  // obs_proj: A = obs (f32, reg-staged+converted in-kernel), B = WeT per-expert
  fgemm<1, true, true, false><<<gg, 256, 0, stream>>>(
      nullptr, obs, (long)NT * NH,
      WeT, (long)NH * NH, 0,
      op_b, hbuf, (long)PADT * NH, 1, nullptr, eidx);
  // conv1: kt-outer, 3 dt-panels resident; A = hbuf (padded)
  fgemm<3, false, false, false><<<gg, 256, 0, stream>>>(
      hbuf, nullptr, (long)PADT * NH,
      w1p, 0, (long)NH * NH,
      cb1, ybuf, (long)PADT * NH, 1, nullptr, eidx);
  // conv2 fused with max-pool: per-column max -> pooled (no 33 MB store)
  fgemm<3, false, false, true><<<gg, 256, 0, stream>>>(
      ybuf, nullptr, (long)PADT * NH,
      w2p, 0, (long)NH * NH,
      cb2, nullptr, 0, 0, pooled, eidx);

  // -- tail --
  head1_kernel<<<dim3(NB, 4), 512, 0, stream>>>(pooled, W1T, h1_b, eidx, x1);
  head2_kernel<<<NB, 256, 0, stream>>>(x1, w2f, h2_b, eidx, out);
}